// Round 1
// baseline (206.288 us; speedup 1.0000x reference)
//
#include <hip/hip_runtime.h>
#include <hip/hip_bf16.h>

// EdgeNetwork: B=8, N=256, F_IN=64, F_OUT=64, MID=96
// out[b,n,o] = sum_m tanh( relu( [x_n, x_j(m), e_{b,n,m}] @ W1 + b1 ) @ W2 + b2 )[o]
// Decomposition: block@W1 = A[b,n] + C[b,j] + e * W1[128,:]
//   A[b,n,:] = x_n @ W1[0:64,:]  + b1
//   C[b,j,:] = x_j @ W1[64:128,:]

#define BATCH 8
#define NN 256
#define FIN 64
#define FOUT 64
#define MIDD 96

// ---------------- precompute kernel: A and C ----------------
__global__ __launch_bounds__(192) void edge_pre(
    const float* __restrict__ node,   // (B, N, 64)
    const float* __restrict__ W1,     // (129, 96)
    const float* __restrict__ b1,     // (96,)
    float* __restrict__ A,            // (B*N, 96)
    float* __restrict__ C)            // (B*N, 96)
{
    int bn = blockIdx.x;              // 0 .. B*N-1
    __shared__ float x[FIN];
    int tid = threadIdx.x;
    if (tid < FIN) x[tid] = node[(size_t)bn * FIN + tid];
    __syncthreads();
    if (tid < MIDD) {
        int h = tid;
        float s = b1[h];
#pragma unroll
        for (int f = 0; f < FIN; ++f)
            s = fmaf(x[f], W1[f * MIDD + h], s);
        A[(size_t)bn * MIDD + h] = s;
    } else {
        int h = tid - MIDD;           // 0..95
        float s = 0.f;
#pragma unroll
        for (int f = 0; f < FIN; ++f)
            s = fmaf(x[f], W1[(FIN + f) * MIDD + h], s);
        C[(size_t)bn * MIDD + h] = s;
    }
}

// ---------------- main kernel ----------------
// One block (256 threads = 4 waves) per (b,n). Wave w handles neighbors
// m = it*4 + w. Each wave computes h[96] into its own LDS slice, then each
// lane o does the 96-dot with its register-resident W2 column and
// accumulates tanh.
__global__ __launch_bounds__(256) void edge_main(
    const float* __restrict__ edge,   // (B, N, 255)
    const float* __restrict__ A,      // (B*N, 96)
    const float* __restrict__ C,      // (B*N, 96)
    const float* __restrict__ W1,     // (129, 96) -> row 128 used
    const float* __restrict__ W2,     // (96, 64)
    const float* __restrict__ b2,     // (64,)
    float* __restrict__ out)          // (B, N, 64)
{
    int bn = blockIdx.x;              // 0 .. 2047
    int b  = bn >> 8;
    int n  = bn & 255;

    __shared__ float s_a[MIDD];
    __shared__ float s_w128[MIDD];
    __shared__ float s_h[4][MIDD];
    __shared__ float s_red[4][FOUT];

    int tid  = threadIdx.x;
    int w    = tid >> 6;
    int lane = tid & 63;

    // W2 column `lane` into registers (fully static indexing -> VGPRs)
    float w2c[MIDD];
#pragma unroll
    for (int k = 0; k < MIDD; ++k)
        w2c[k] = W2[k * FOUT + lane];

    if (tid < MIDD) s_a[tid] = A[(size_t)bn * MIDD + tid];
    else if (tid < 2 * MIDD) s_w128[tid - MIDD] = W1[128 * MIDD + (tid - MIDD)];

    float bb2 = b2[lane];
    __syncthreads();

    const float* Cb = C + (size_t)b * NN * MIDD;
    const float* eg = edge + (size_t)bn * (NN - 1);

    float acc = 0.f;

    for (int it = 0; it < 64; ++it) {
        int m = it * 4 + w;
        bool active = (m < NN - 1);
        if (active) {
            int j = (m < n) ? m : m + 1;
            float e = eg[m];
            const float* Cj = Cb + (size_t)j * MIDD;
            float h0 = s_a[lane] + Cj[lane] + e * s_w128[lane];
            s_h[w][lane] = fmaxf(h0, 0.f);
            if (lane < MIDD - 64) {
                float h1 = s_a[lane + 64] + Cj[lane + 64] + e * s_w128[lane + 64];
                s_h[w][lane + 64] = fmaxf(h1, 0.f);
            }
        }
        // within-wave LDS write->read ordering (lockstep wave64, no barrier
        // needed; memory clobber keeps the ds ops ordered around the wait)
        asm volatile("s_waitcnt lgkmcnt(0)" ::: "memory");
        if (active) {
            float v = bb2;
#pragma unroll
            for (int k = 0; k < MIDD; ++k)
                v = fmaf(s_h[w][k], w2c[k], v);
            acc += tanhf(v);
        }
    }

    // cross-wave reduction
    s_red[w][lane] = acc;
    __syncthreads();
    if (w == 0) {
        float r = s_red[0][lane] + s_red[1][lane] + s_red[2][lane] + s_red[3][lane];
        out[(size_t)bn * FOUT + lane] = r;
    }
}

extern "C" void kernel_launch(void* const* d_in, const int* in_sizes, int n_in,
                              void* d_out, int out_size, void* d_ws, size_t ws_size,
                              hipStream_t stream) {
    const float* inp_node = (const float*)d_in[0];  // (8,256,64)
    const float* inp_edge = (const float*)d_in[1];  // (8,256,255)
    const float* W1       = (const float*)d_in[2];  // (129,96)
    const float* b1       = (const float*)d_in[3];  // (96,)
    const float* W2       = (const float*)d_in[4];  // (96,64)
    const float* b2       = (const float*)d_in[5];  // (64,)
    float* out            = (float*)d_out;          // (8,256,64)

    float* A = (float*)d_ws;                               // 2048*96 floats
    float* C = A + (size_t)BATCH * NN * MIDD;              // 2048*96 floats

    edge_pre<<<BATCH * NN, 192, 0, stream>>>(inp_node, W1, b1, A, C);
    edge_main<<<BATCH * NN, 256, 0, stream>>>(inp_edge, A, C, W1, W2, b2, out);
}

// Round 2
// 47.206 us; speedup vs baseline: 4.3700x; 4.3700x over previous
//
#include <hip/hip_runtime.h>
#include <hip/hip_bf16.h>

// EdgeNetwork: B=8, N=256, F_IN=64, F_OUT=64, MID=96
// out[b,n,o] = sum_m tanh( relu( [x_n, x_j(m), e_{b,n,m}] @ W1 + b1 ) @ W2 + b2 )[o]
// Decomposition: H[m,:] = A[b,n,:] + C[b,j(m),:] + e[m]*W1[128,:]  (j = m + (m>=n))
//   A[b,n,:] = x_n @ W1[0:64,:] + b1   (precomputed, f32)
//   C[b,j,:] = x_j @ W1[64:128,:]      (precomputed, f32)
// Then per (b,n): out = sum_rows tanh( relu(H) @ W2 + b2 )  -> bf16 MFMA GEMM.

#define BATCH 8
#define NN 256
#define FIN 64
#define FOUT 64
#define MIDD 96
#define PADK 104   // bf16 elems per padded row: 208 B, 16B-aligned, bank-uniform

typedef __attribute__((ext_vector_type(8))) short short8;  // 8 bf16 (4 VGPRs)
typedef __attribute__((ext_vector_type(4))) float f32x4;

__device__ __forceinline__ unsigned pack_bf16(float lo, float hi) {
    __hip_bfloat162 h2 = __float22bfloat162_rn(make_float2(lo, hi));
    union { __hip_bfloat162 h; unsigned u; } cv; cv.h = h2;
    return cv.u;   // lo in low 16 bits
}

// ---------------- precompute: A, C (f32) and W2T (bf16, padded) ----------------
__global__ __launch_bounds__(192) void edge_pre(
    const float* __restrict__ node,   // (B,N,64)
    const float* __restrict__ W1,     // (129,96)
    const float* __restrict__ b1,     // (96,)
    const float* __restrict__ W2,     // (96,64)
    float* __restrict__ A,            // (B*N,96)
    float* __restrict__ C,            // (B*N,96)
    unsigned short* __restrict__ W2T) // (64, PADK) bf16
{
    int blk = blockIdx.x;
    int tid = threadIdx.x;
    if (blk == BATCH * NN) {
        // transpose W2 -> W2T[c][k] = bf16(W2[k][c])
        for (int idx = tid; idx < MIDD * FOUT; idx += 192) {
            int k = idx >> 6, c = idx & 63;
            union { __hip_bfloat16 h; unsigned short u; } cv;
            cv.h = __float2bfloat16(W2[idx]);
            W2T[c * PADK + k] = cv.u;
        }
        return;
    }
    __shared__ float x[FIN];
    if (tid < FIN) x[tid] = node[(size_t)blk * FIN + tid];
    __syncthreads();
    if (tid < MIDD) {
        int h = tid;
        float s = b1[h];
#pragma unroll
        for (int f = 0; f < FIN; ++f) s = fmaf(x[f], W1[f * MIDD + h], s);
        A[(size_t)blk * MIDD + h] = s;
    } else {
        int h = tid - MIDD;
        float s = 0.f;
#pragma unroll
        for (int f = 0; f < FIN; ++f) s = fmaf(x[f], W1[(FIN + f) * MIDD + h], s);
        C[(size_t)blk * MIDD + h] = s;
    }
}

// ---------------- main: per (b,n) MFMA GEMM + tanh + row-sum ----------------
__global__ __launch_bounds__(256) void edge_main(
    const float* __restrict__ edge,          // (B,N,255)
    const float* __restrict__ A,             // (B*N,96)
    const float* __restrict__ C,             // (B*N,96)
    const float* __restrict__ W1,            // row 128 = edge weight
    const unsigned short* __restrict__ W2Tg, // (64,PADK) bf16
    const float* __restrict__ b2,            // (64,)
    float* __restrict__ out)                 // (B,N,64)
{
    __shared__ unsigned short s_h[64][PADK];    // H chunk (64 rows) bf16
    __shared__ unsigned short s_w2t[FOUT][PADK];// W2^T bf16
    __shared__ float s_red[4][FOUT];

    int bn = blockIdx.x, b = bn >> 8, n = bn & 255;
    int tid = threadIdx.x;
    int w = tid >> 6, lane = tid & 63;
    int lo16 = lane & 15, hi = lane >> 4;

    // stage W2T -> LDS (832 x 16B)
    {
        const uint4* g = (const uint4*)W2Tg;
        uint4* s = (uint4*)&s_w2t[0][0];
#pragma unroll
        for (int i = 0; i < 4; ++i) {
            int idx = i * 256 + tid;
            if (idx < (FOUT * PADK * 2) / 16) s[idx] = g[idx];
        }
    }

    // H-compute thread mapping: row r = tid>>2 (0..63), col quarter q = tid&3
    int r = tid >> 2;
    int q = tid & 3;
    float Aq[24], Wq[24];
    {
        const float4* Ap = (const float4*)(A + (size_t)bn * MIDD + q * 24);
        const float4* Wp = (const float4*)(W1 + 128 * MIDD + q * 24);
#pragma unroll
        for (int i = 0; i < 6; ++i) {
            float4 a4 = Ap[i], w4 = Wp[i];
            Aq[i*4+0]=a4.x; Aq[i*4+1]=a4.y; Aq[i*4+2]=a4.z; Aq[i*4+3]=a4.w;
            Wq[i*4+0]=w4.x; Wq[i*4+1]=w4.y; Wq[i*4+2]=w4.z; Wq[i*4+3]=w4.w;
        }
    }

    float b2c[4];
#pragma unroll
    for (int nt = 0; nt < 4; ++nt) b2c[nt] = b2[nt * 16 + lo16];

    __syncthreads();

    // hoisted B fragments: bf[nt][ks] lane holds W2[ks*32+hi*8+j][nt*16+lo16]
    short8 bf[4][3];
#pragma unroll
    for (int nt = 0; nt < 4; ++nt)
#pragma unroll
        for (int ks = 0; ks < 3; ++ks)
            bf[nt][ks] = *(const short8*)&s_w2t[nt * 16 + lo16][ks * 32 + hi * 8];

    const float* Cb = C + (size_t)b * NN * MIDD;
    const float* eg = edge + (size_t)bn * (NN - 1);

    float sum4[4] = {0.f, 0.f, 0.f, 0.f};

    for (int chunk = 0; chunk < 4; ++chunk) {
        // ---- build H chunk (bf16) ----
        int m = chunk * 64 + r;
        unsigned short* dst = &s_h[r][q * 24];
        if (m == NN - 1) {
            uint4 z = make_uint4(0u, 0u, 0u, 0u);
            ((uint4*)dst)[0] = z; ((uint4*)dst)[1] = z; ((uint4*)dst)[2] = z;
        } else {
            int j = m + (m >= n);
            float e = eg[m];
            const float4* Cv = (const float4*)(Cb + (size_t)j * MIDD + q * 24);
            float h[24];
#pragma unroll
            for (int i = 0; i < 6; ++i) {
                float4 c4 = Cv[i];
                h[i*4+0] = fmaxf(fmaf(e, Wq[i*4+0], Aq[i*4+0] + c4.x), 0.f);
                h[i*4+1] = fmaxf(fmaf(e, Wq[i*4+1], Aq[i*4+1] + c4.y), 0.f);
                h[i*4+2] = fmaxf(fmaf(e, Wq[i*4+2], Aq[i*4+2] + c4.z), 0.f);
                h[i*4+3] = fmaxf(fmaf(e, Wq[i*4+3], Aq[i*4+3] + c4.w), 0.f);
            }
#pragma unroll
            for (int s3 = 0; s3 < 3; ++s3) {
                uint4 u;
                u.x = pack_bf16(h[s3*8+0], h[s3*8+1]);
                u.y = pack_bf16(h[s3*8+2], h[s3*8+3]);
                u.z = pack_bf16(h[s3*8+4], h[s3*8+5]);
                u.w = pack_bf16(h[s3*8+6], h[s3*8+7]);
                ((uint4*)dst)[s3] = u;
            }
        }
        __syncthreads();

        // ---- MFMA: wave w owns rows [w*16, w*16+16) of the chunk ----
        short8 af[3];
#pragma unroll
        for (int ks = 0; ks < 3; ++ks)
            af[ks] = *(const short8*)&s_h[w * 16 + lo16][ks * 32 + hi * 8];

        f32x4 acc[4] = {{0.f,0.f,0.f,0.f},{0.f,0.f,0.f,0.f},
                        {0.f,0.f,0.f,0.f},{0.f,0.f,0.f,0.f}};
#pragma unroll
        for (int ks = 0; ks < 3; ++ks)
#pragma unroll
            for (int nt = 0; nt < 4; ++nt)
                acc[nt] = __builtin_amdgcn_mfma_f32_16x16x32_bf16(
                    af[ks], bf[nt][ks], acc[nt], 0, 0, 0);

        // ---- tanh + accumulate column sums (D: row=(hi*4+r4), col=lo16) ----
        int mbase = chunk * 64 + w * 16 + hi * 4;
#pragma unroll
        for (int nt = 0; nt < 4; ++nt) {
#pragma unroll
            for (int r4 = 0; r4 < 4; ++r4) {
                if (mbase + r4 < NN - 1) {
                    float v = acc[nt][r4] + b2c[nt];
                    float ex = __expf(2.f * v);
                    sum4[nt] += fmaf(-2.f, __fdividef(1.f, ex + 1.f), 1.f);
                }
            }
        }
        __syncthreads();   // protect s_h before next chunk overwrite
    }

    // reduce over row-groups (hi) within wave
#pragma unroll
    for (int nt = 0; nt < 4; ++nt) {
        sum4[nt] += __shfl_xor(sum4[nt], 16);
        sum4[nt] += __shfl_xor(sum4[nt], 32);
    }
    if (hi == 0) {
#pragma unroll
        for (int nt = 0; nt < 4; ++nt)
            s_red[w][nt * 16 + lo16] = sum4[nt];
    }
    __syncthreads();
    if (tid < FOUT)
        out[(size_t)bn * FOUT + tid] =
            s_red[0][tid] + s_red[1][tid] + s_red[2][tid] + s_red[3][tid];
}

extern "C" void kernel_launch(void* const* d_in, const int* in_sizes, int n_in,
                              void* d_out, int out_size, void* d_ws, size_t ws_size,
                              hipStream_t stream) {
    const float* inp_node = (const float*)d_in[0];  // (8,256,64)
    const float* inp_edge = (const float*)d_in[1];  // (8,256,255)
    const float* W1       = (const float*)d_in[2];  // (129,96)
    const float* b1       = (const float*)d_in[3];  // (96,)
    const float* W2       = (const float*)d_in[4];  // (96,64)
    const float* b2       = (const float*)d_in[5];  // (64,)
    float* out            = (float*)d_out;          // (8,256,64)

    float* A = (float*)d_ws;                                   // 2048*96 f32
    float* C = A + (size_t)BATCH * NN * MIDD;                  // 2048*96 f32
    unsigned short* W2T = (unsigned short*)(C + (size_t)BATCH * NN * MIDD); // 64*PADK bf16

    edge_pre<<<BATCH * NN + 1, 192, 0, stream>>>(inp_node, W1, b1, W2, A, C, W2T);
    edge_main<<<BATCH * NN, 256, 0, stream>>>(inp_edge, A, C, W1, W2T, b2, out);
}

// Round 5
// 46.730 us; speedup vs baseline: 4.4144x; 1.0102x over previous
//
#include <hip/hip_runtime.h>
#include <hip/hip_bf16.h>

// EdgeNetwork: B=8, N=256, F_IN=64, F_OUT=64, MID=96
// out[b,n,o] = sum_m tanh( relu( [x_n, x_j(m), e_{b,n,m}] @ W1 + b1 ) @ W2 + b2 )[o]
// H[m,:] = A[b,n,:] + C[b,j(m),:] + e[m]*W1[128,:],  j = m + (m>=n)
// Per (b,n): out = sum_rows tanh( relu(H) @ W2 + b2 ) via bf16 MFMA,
// A-fragments built directly in registers (no LDS, no barriers in main loop).
// tanh(v) = 1 - 2r, r = 1/(1+exp(2v));  out = 256 - 2*sum(r) with the
// invalid row-255 slot's r forced to 0.5.

#define BATCH 8
#define NN 256
#define FIN 64
#define FOUT 64
#define MIDD 96
#define PADK 104   // bf16 elems per padded W2T row (208 B, 16B-aligned)

typedef __attribute__((ext_vector_type(8))) short short8;  // 8 bf16
typedef __attribute__((ext_vector_type(4))) float f32x4;

#if __has_builtin(__builtin_amdgcn_exp2f)
#define EXP2F(x) __builtin_amdgcn_exp2f(x)
#else
#define EXP2F(x) exp2f(x)
#endif
#if __has_builtin(__builtin_amdgcn_rcpf)
#define RCPF(x) __builtin_amdgcn_rcpf(x)
#else
#define RCPF(x) (1.0f / (x))
#endif

#define TWO_LOG2E 2.8853900817779268f

__device__ __forceinline__ unsigned pack_bf16(float lo, float hi) {
    __hip_bfloat162 h2 = __float22bfloat162_rn(make_float2(lo, hi));
    union { __hip_bfloat162 h; unsigned u; } cv; cv.h = h2;
    return cv.u;
}

// ---------------- precompute: A, C (f32) and W2T (bf16, padded) ----------------
__global__ __launch_bounds__(192) void edge_pre(
    const float* __restrict__ node,   // (B,N,64)
    const float* __restrict__ W1,     // (129,96)
    const float* __restrict__ b1,     // (96,)
    const float* __restrict__ W2,     // (96,64)
    float* __restrict__ A,            // (B*N,96)
    float* __restrict__ C,            // (B*N,96)
    unsigned short* __restrict__ W2T) // (64, PADK) bf16
{
    int blk = blockIdx.x;
    int tid = threadIdx.x;
    if (blk == BATCH * NN) {
        for (int idx = tid; idx < MIDD * FOUT; idx += 192) {
            int k = idx >> 6, c = idx & 63;
            union { __hip_bfloat16 h; unsigned short u; } cv;
            cv.h = __float2bfloat16(W2[idx]);
            W2T[c * PADK + k] = cv.u;
        }
        return;
    }
    __shared__ float x[FIN];
    if (tid < FIN) x[tid] = node[(size_t)blk * FIN + tid];
    __syncthreads();
    if (tid < MIDD) {
        int h = tid;
        float s = b1[h];
#pragma unroll
        for (int f = 0; f < FIN; ++f) s = fmaf(x[f], W1[f * MIDD + h], s);
        A[(size_t)blk * MIDD + h] = s;
    } else {
        int h = tid - MIDD;
        float s = 0.f;
#pragma unroll
        for (int f = 0; f < FIN; ++f) s = fmaf(x[f], W1[(FIN + f) * MIDD + h], s);
        C[(size_t)blk * MIDD + h] = s;
    }
}

// per-lane C-row slice loader for one chunk
__device__ __forceinline__ void load_chunk(
    int chunk, int w, int lo16, int hi, int n,
    const float* __restrict__ Cb, const float* __restrict__ eg,
    float* cb, float& e, unsigned& msk)
{
    int m = chunk * 64 + w * 16 + lo16;
    bool valid = (m < NN - 1);
    msk = valid ? 0xFFFFFFFFu : 0u;
    int j = m + ((m >= n) ? 1 : 0);
    j = (j > 255) ? 255 : j;
    e = eg[valid ? m : (NN - 2)];
    const float* Cj = Cb + (size_t)j * MIDD;
#pragma unroll
    for (int ks = 0; ks < 3; ++ks) {
        int k0 = ks * 32 + hi * 8;
        float4 c0 = *(const float4*)(Cj + k0);
        float4 c1 = *(const float4*)(Cj + k0 + 4);
        cb[ks*8+0] = c0.x; cb[ks*8+1] = c0.y; cb[ks*8+2] = c0.z; cb[ks*8+3] = c0.w;
        cb[ks*8+4] = c1.x; cb[ks*8+5] = c1.y; cb[ks*8+6] = c1.z; cb[ks*8+7] = c1.w;
    }
}

// ---------------- main: register-resident fragments, no main-loop barriers ----
__global__ __launch_bounds__(256, 2) void edge_main(
    const float* __restrict__ edge,          // (B,N,255)
    const float* __restrict__ A,             // (B*N,96)
    const float* __restrict__ C,             // (B*N,96)
    const float* __restrict__ W1,            // row 128 used
    const unsigned short* __restrict__ W2Tg, // (64,PADK) bf16
    const float* __restrict__ b2,            // (64,)
    float* __restrict__ out)                 // (B,N,64)
{
    __shared__ float s_red[4][FOUT];

    int bn = blockIdx.x, b = bn >> 8, n = bn & 255;
    int tid = threadIdx.x;
    int w = tid >> 6, lane = tid & 63;
    int lo16 = lane & 15, hi = lane >> 4;

    // per-lane k-slices of A-row and W1[128]: k = ks*32 + hi*8 + 0..7
    float A24[24], W24[24];
    {
        const float* Abase = A + (size_t)bn * MIDD;
        const float* Wbase = W1 + 128 * MIDD;
#pragma unroll
        for (int ks = 0; ks < 3; ++ks) {
            int k0 = ks * 32 + hi * 8;
            float4 a0 = *(const float4*)(Abase + k0);
            float4 a1 = *(const float4*)(Abase + k0 + 4);
            float4 w0 = *(const float4*)(Wbase + k0);
            float4 w1 = *(const float4*)(Wbase + k0 + 4);
            A24[ks*8+0]=a0.x; A24[ks*8+1]=a0.y; A24[ks*8+2]=a0.z; A24[ks*8+3]=a0.w;
            A24[ks*8+4]=a1.x; A24[ks*8+5]=a1.y; A24[ks*8+6]=a1.z; A24[ks*8+7]=a1.w;
            W24[ks*8+0]=w0.x; W24[ks*8+1]=w0.y; W24[ks*8+2]=w0.z; W24[ks*8+3]=w0.w;
            W24[ks*8+4]=w1.x; W24[ks*8+5]=w1.y; W24[ks*8+6]=w1.z; W24[ks*8+7]=w1.w;
        }
    }

    // B fragments straight from global (L2-resident)
    short8 bf[4][3];
#pragma unroll
    for (int nt = 0; nt < 4; ++nt)
#pragma unroll
        for (int ks = 0; ks < 3; ++ks)
            bf[nt][ks] = *(const short8*)&W2Tg[(nt * 16 + lo16) * PADK + ks * 32 + hi * 8];

    float c2[4];   // 2*log2(e) * b2[col]
#pragma unroll
    for (int nt = 0; nt < 4; ++nt) c2[nt] = TWO_LOG2E * b2[nt * 16 + lo16];

    const float* Cb = C + (size_t)b * NN * MIDD;
    const float* eg = edge + (size_t)bn * (NN - 1);

    float Rs[4] = {0.f, 0.f, 0.f, 0.f};

    float cb[24]; float ec; unsigned mc;
    load_chunk(0, w, lo16, hi, n, Cb, eg, cb, ec, mc);

#pragma unroll
    for (int chunk = 0; chunk < 4; ++chunk) {
        float cn[24]; float en; unsigned mn;
        if (chunk < 3) load_chunk(chunk + 1, w, lo16, hi, n, Cb, eg, cn, en, mn);

        // build A-fragments in registers
        short8 af[3];
#pragma unroll
        for (int ks = 0; ks < 3; ++ks) {
            float h[8];
#pragma unroll
            for (int i = 0; i < 8; ++i)
                h[i] = fmaxf(fmaf(ec, W24[ks*8+i], A24[ks*8+i] + cb[ks*8+i]), 0.f);
            union { unsigned u[4]; short8 s; } cv;
            cv.u[0] = pack_bf16(h[0], h[1]) & mc;
            cv.u[1] = pack_bf16(h[2], h[3]) & mc;
            cv.u[2] = pack_bf16(h[4], h[5]) & mc;
            cv.u[3] = pack_bf16(h[6], h[7]) & mc;
            af[ks] = cv.s;
        }

        f32x4 acc[4] = {{0.f,0.f,0.f,0.f},{0.f,0.f,0.f,0.f},
                        {0.f,0.f,0.f,0.f},{0.f,0.f,0.f,0.f}};
#pragma unroll
        for (int ks = 0; ks < 3; ++ks)
#pragma unroll
            for (int nt = 0; nt < 4; ++nt)
                acc[nt] = __builtin_amdgcn_mfma_f32_16x16x32_bf16(
                    af[ks], bf[nt][ks], acc[nt], 0, 0, 0);

        // r = 1/(1+exp(2v)); accumulate
#pragma unroll
        for (int nt = 0; nt < 4; ++nt)
#pragma unroll
            for (int r4 = 0; r4 < 4; ++r4) {
                float arg = fmaf(acc[nt][r4], TWO_LOG2E, c2[nt]);
                float ex = EXP2F(arg);
                Rs[nt] += RCPF(1.f + ex);
            }

        if (chunk < 3) {
#pragma unroll
            for (int i = 0; i < 24; ++i) cb[i] = cn[i];
            ec = en; mc = mn;
        }
    }

    // row-255 slot was computed with H=0 -> r = 1/(1+exp2(c2)); force to 0.5
    if (w == 3 && hi == 3) {
#pragma unroll
        for (int nt = 0; nt < 4; ++nt) {
            float r255 = RCPF(1.f + EXP2F(c2[nt]));
            Rs[nt] += 0.5f - r255;
        }
    }

    // reduce: across hi groups (rows) then across waves
#pragma unroll
    for (int nt = 0; nt < 4; ++nt) {
        Rs[nt] += __shfl_xor(Rs[nt], 16);
        Rs[nt] += __shfl_xor(Rs[nt], 32);
    }
    if (hi == 0) {
#pragma unroll
        for (int nt = 0; nt < 4; ++nt) s_red[w][nt * 16 + lo16] = Rs[nt];
    }
    __syncthreads();
    if (tid < FOUT) {
        float t = s_red[0][tid] + s_red[1][tid] + s_red[2][tid] + s_red[3][tid];
        out[(size_t)bn * FOUT + tid] = fmaf(-2.f, t, 256.f);
    }
}

extern "C" void kernel_launch(void* const* d_in, const int* in_sizes, int n_in,
                              void* d_out, int out_size, void* d_ws, size_t ws_size,
                              hipStream_t stream) {
    const float* inp_node = (const float*)d_in[0];  // (8,256,64)
    const float* inp_edge = (const float*)d_in[1];  // (8,256,255)
    const float* W1       = (const float*)d_in[2];  // (129,96)
    const float* b1       = (const float*)d_in[3];  // (96,)
    const float* W2       = (const float*)d_in[4];  // (96,64)
    const float* b2       = (const float*)d_in[5];  // (64,)
    float* out            = (float*)d_out;          // (8,256,64)

    float* A = (float*)d_ws;                                   // 2048*96 f32
    float* C = A + (size_t)BATCH * NN * MIDD;                  // 2048*96 f32
    unsigned short* W2T = (unsigned short*)(C + (size_t)BATCH * NN * MIDD);

    edge_pre<<<BATCH * NN + 1, 192, 0, stream>>>(inp_node, W1, b1, W2, A, C, W2T);
    edge_main<<<BATCH * NN, 256, 0, stream>>>(inp_edge, A, C, W1, W2T, b2, out);
}

// Round 7
// 38.463 us; speedup vs baseline: 5.3633x; 1.2150x over previous
//
#include <hip/hip_runtime.h>
#include <hip/hip_bf16.h>

// EdgeNetwork: B=8, N=256, F_IN=64, F_OUT=64, MID=96
// out[b,n,o] = sum_m tanh( relu( [x_n, x_j(m), e_{b,n,m}] @ W1 + b1 ) @ W2 + b2 )[o]
// H[m,:] = A[b,n,:] + C[b,j(m),:] + e[m]*W1[128,:],  j = m + (m>=n)
// R6: per-block LDS staging of C[b] (bf16, row-padded to 104) shared by 4 n's.
// Kills the scattered-global C gather (TA address-divergence bound in R2/R5):
// staging is coalesced, per-row gather becomes near-conflict-free ds_read_b128.
// tanh(v) = 1 - 2r, r = 1/(1+exp(2v));  out = 256 - 2*sum(r), invalid slot -> 0.5.

#define BATCH 8
#define NN 256
#define FIN 64
#define FOUT 64
#define MIDD 96
#define CPAD 104   // bf16 elems per padded row (208 B: 16B-aligned, 2-way-max banks)
#define NG 4       // n-values per block

typedef __attribute__((ext_vector_type(8))) short short8;  // 8 bf16
typedef __attribute__((ext_vector_type(4))) float f32x4;

#if __has_builtin(__builtin_amdgcn_exp2f)
#define EXP2F(x) __builtin_amdgcn_exp2f(x)
#else
#define EXP2F(x) exp2f(x)
#endif
#if __has_builtin(__builtin_amdgcn_rcpf)
#define RCPF(x) __builtin_amdgcn_rcpf(x)
#else
#define RCPF(x) (1.0f / (x))
#endif

#define TWO_LOG2E 2.8853900817779268f

__device__ __forceinline__ unsigned pack_bf16(float lo, float hi) {
    __hip_bfloat162 h2 = __float22bfloat162_rn(make_float2(lo, hi));
    union { __hip_bfloat162 h; unsigned u; } cv; cv.h = h2;
    return cv.u;
}

// ------------- precompute: A (f32), C (bf16 padded), W2T (bf16 padded) -------
__global__ __launch_bounds__(192) void edge_pre(
    const float* __restrict__ node,    // (B,N,64)
    const float* __restrict__ W1,      // (129,96)
    const float* __restrict__ b1,      // (96,)
    const float* __restrict__ W2,      // (96,64)
    float* __restrict__ A,             // (B*N,96) f32
    unsigned short* __restrict__ Cb16, // (B, N, CPAD) bf16
    unsigned short* __restrict__ W2T)  // (64, CPAD) bf16
{
    int blk = blockIdx.x;
    int tid = threadIdx.x;
    if (blk == BATCH * NN) {
        for (int idx = tid; idx < FOUT * CPAD; idx += 192) {
            int c = idx / CPAD, k = idx % CPAD;
            float v = (k < MIDD) ? W2[k * FOUT + c] : 0.f;
            union { __hip_bfloat16 h; unsigned short u; } cv;
            cv.h = __float2bfloat16(v);
            W2T[idx] = cv.u;
        }
        return;
    }
    __shared__ float x[FIN];
    if (tid < FIN) x[tid] = node[(size_t)blk * FIN + tid];
    __syncthreads();
    if (tid < MIDD) {
        int h = tid;
        float s = b1[h];
#pragma unroll
        for (int f = 0; f < FIN; ++f) s = fmaf(x[f], W1[f * MIDD + h], s);
        A[(size_t)blk * MIDD + h] = s;
    } else {
        int h = tid - MIDD;   // 0..95
        float s = 0.f;
#pragma unroll
        for (int f = 0; f < FIN; ++f) s = fmaf(x[f], W1[(FIN + f) * MIDD + h], s);
        union { __hip_bfloat16 hh; unsigned short u; } cv;
        cv.hh = __float2bfloat16(s);
        Cb16[(size_t)blk * CPAD + h] = cv.u;
        if (h < CPAD - MIDD) Cb16[(size_t)blk * CPAD + MIDD + h] = 0;  // pad
    }
}

// ------------- main: LDS-staged C[b], 4 n's per block --------------------------
__global__ __launch_bounds__(256, 2) void edge_main2(
    const float* __restrict__ edge,          // (B,N,255)
    const float* __restrict__ A,             // (B*N,96)
    const unsigned short* __restrict__ Cb16, // (B,N,CPAD) bf16
    const float* __restrict__ W1,            // row 128 used
    const unsigned short* __restrict__ W2T,  // (64,CPAD) bf16
    const float* __restrict__ b2,            // (64,)
    float* __restrict__ out)                 // (B,N,64)
{
    __shared__ unsigned short sC[NN * CPAD];   // 53248 B
    __shared__ float s_red[4][FOUT];

    int blk = blockIdx.x;             // 0..511
    int b = blk >> 6;
    int n0 = (blk & 63) << 2;
    int tid = threadIdx.x;
    int w = tid >> 6, lane = tid & 63;
    int lo16 = lane & 15, hi = lane >> 4;

    // stage C[b] -> LDS, fully coalesced (3328 uint4)
    {
        const uint4* src = (const uint4*)(Cb16 + (size_t)b * NN * CPAD);
        uint4* dst = (uint4*)sC;
#pragma unroll
        for (int i = 0; i < 13; ++i) dst[i * 256 + tid] = src[i * 256 + tid];
    }

    // per-lane k-slices of W1[128]: k = ks*32 + hi*8 + 0..7
    float W24[24];
    {
        const float* Wbase = W1 + 128 * MIDD;
#pragma unroll
        for (int ks = 0; ks < 3; ++ks) {
            int k0 = ks * 32 + hi * 8;
            float4 w0 = *(const float4*)(Wbase + k0);
            float4 w1 = *(const float4*)(Wbase + k0 + 4);
            W24[ks*8+0]=w0.x; W24[ks*8+1]=w0.y; W24[ks*8+2]=w0.z; W24[ks*8+3]=w0.w;
            W24[ks*8+4]=w1.x; W24[ks*8+5]=w1.y; W24[ks*8+6]=w1.z; W24[ks*8+7]=w1.w;
        }
    }

    // B fragments from global W2T (one-time)
    short8 bf[4][3];
#pragma unroll
    for (int nt = 0; nt < 4; ++nt)
#pragma unroll
        for (int ks = 0; ks < 3; ++ks)
            bf[nt][ks] = *(const short8*)&W2T[(nt * 16 + lo16) * CPAD + ks * 32 + hi * 8];

    float c2[4];   // 2*log2(e) * b2[col]
#pragma unroll
    for (int nt = 0; nt < 4; ++nt) c2[nt] = TWO_LOG2E * b2[nt * 16 + lo16];

    __syncthreads();

#pragma unroll 1
    for (int nl = 0; nl < NG; ++nl) {
        int n = n0 + nl;
        int bn = (b << 8) + n;

        // A-row slices (f32, broadcast across lo16 -> cheap)
        float A24[24];
        {
            const float* Abase = A + (size_t)bn * MIDD;
#pragma unroll
            for (int ks = 0; ks < 3; ++ks) {
                int k0 = ks * 32 + hi * 8;
                float4 a0 = *(const float4*)(Abase + k0);
                float4 a1 = *(const float4*)(Abase + k0 + 4);
                A24[ks*8+0]=a0.x; A24[ks*8+1]=a0.y; A24[ks*8+2]=a0.z; A24[ks*8+3]=a0.w;
                A24[ks*8+4]=a1.x; A24[ks*8+5]=a1.y; A24[ks*8+6]=a1.z; A24[ks*8+7]=a1.w;
            }
        }
        const float* eg = edge + (size_t)bn * (NN - 1);

        float Rs[4] = {0.f, 0.f, 0.f, 0.f};

#pragma unroll
        for (int chunk = 0; chunk < 4; ++chunk) {
            int m = chunk * 64 + w * 16 + lo16;
            bool valid = (m < NN - 1);
            unsigned mc = valid ? 0xFFFFFFFFu : 0u;
            int j = m + ((m >= n) ? 1 : 0);
            j = (j > 255) ? 255 : j;
            float e = eg[valid ? m : (NN - 3)];
            const unsigned short* crow = &sC[j * CPAD + hi * 8];

            short8 af[3];
#pragma unroll
            for (int ks = 0; ks < 3; ++ks) {
                uint4 q = *(const uint4*)(crow + ks * 32);   // ds_read_b128
                float c[8];
                c[0] = __uint_as_float(q.x << 16);
                c[1] = __uint_as_float(q.x & 0xFFFF0000u);
                c[2] = __uint_as_float(q.y << 16);
                c[3] = __uint_as_float(q.y & 0xFFFF0000u);
                c[4] = __uint_as_float(q.z << 16);
                c[5] = __uint_as_float(q.z & 0xFFFF0000u);
                c[6] = __uint_as_float(q.w << 16);
                c[7] = __uint_as_float(q.w & 0xFFFF0000u);
                float h[8];
#pragma unroll
                for (int i = 0; i < 8; ++i)
                    h[i] = fmaxf(fmaf(e, W24[ks*8+i], A24[ks*8+i] + c[i]), 0.f);
                union { unsigned u[4]; short8 s; } cv;
                cv.u[0] = pack_bf16(h[0], h[1]) & mc;
                cv.u[1] = pack_bf16(h[2], h[3]) & mc;
                cv.u[2] = pack_bf16(h[4], h[5]) & mc;
                cv.u[3] = pack_bf16(h[6], h[7]) & mc;
                af[ks] = cv.s;
            }

            f32x4 acc[4] = {{0.f,0.f,0.f,0.f},{0.f,0.f,0.f,0.f},
                            {0.f,0.f,0.f,0.f},{0.f,0.f,0.f,0.f}};
#pragma unroll
            for (int ks = 0; ks < 3; ++ks)
#pragma unroll
                for (int nt = 0; nt < 4; ++nt)
                    acc[nt] = __builtin_amdgcn_mfma_f32_16x16x32_bf16(
                        af[ks], bf[nt][ks], acc[nt], 0, 0, 0);

            // r = 1/(1+exp(2v)); accumulate
#pragma unroll
            for (int nt = 0; nt < 4; ++nt)
#pragma unroll
                for (int r4 = 0; r4 < 4; ++r4) {
                    float arg = fmaf(acc[nt][r4], TWO_LOG2E, c2[nt]);
                    Rs[nt] += RCPF(1.f + EXP2F(arg));
                }
        }

        // invalid slot (m=255, D-row hi*4+r4==15) computed r255; force to 0.5
        if (w == 3 && hi == 3) {
#pragma unroll
            for (int nt = 0; nt < 4; ++nt) {
                float r255 = RCPF(1.f + EXP2F(c2[nt]));
                Rs[nt] += 0.5f - r255;
            }
        }

        // reduce across hi groups then waves
#pragma unroll
        for (int nt = 0; nt < 4; ++nt) {
            Rs[nt] += __shfl_xor(Rs[nt], 16);
            Rs[nt] += __shfl_xor(Rs[nt], 32);
        }
        if (hi == 0) {
#pragma unroll
            for (int nt = 0; nt < 4; ++nt) s_red[w][nt * 16 + lo16] = Rs[nt];
        }
        __syncthreads();
        if (tid < FOUT) {
            float t = s_red[0][tid] + s_red[1][tid] + s_red[2][tid] + s_red[3][tid];
            out[(size_t)bn * FOUT + tid] = fmaf(-2.f, t, 256.f);
        }
        __syncthreads();   // s_red reuse by next nl
    }
}

extern "C" void kernel_launch(void* const* d_in, const int* in_sizes, int n_in,
                              void* d_out, int out_size, void* d_ws, size_t ws_size,
                              hipStream_t stream) {
    const float* inp_node = (const float*)d_in[0];  // (8,256,64)
    const float* inp_edge = (const float*)d_in[1];  // (8,256,255)
    const float* W1       = (const float*)d_in[2];  // (129,96)
    const float* b1       = (const float*)d_in[3];  // (96,)
    const float* W2       = (const float*)d_in[4];  // (96,64)
    const float* b2       = (const float*)d_in[5];  // (64,)
    float* out            = (float*)d_out;          // (8,256,64)

    float* A = (float*)d_ws;                                        // 2048*96 f32
    unsigned short* Cb16 = (unsigned short*)(A + (size_t)BATCH * NN * MIDD); // 2048*CPAD bf16
    unsigned short* W2T  = Cb16 + (size_t)BATCH * NN * CPAD;        // 64*CPAD bf16

    edge_pre<<<BATCH * NN + 1, 192, 0, stream>>>(inp_node, W1, b1, W2, A, Cb16, W2T);
    edge_main2<<<BATCH * (NN / NG), 256, 0, stream>>>(inp_edge, A, Cb16, W1, W2T, b2, out);
}